// Round 1
// baseline (1319.906 us; speedup 1.0000x reference)
//
#include <hip/hip_runtime.h>
#include <math.h>

// Problem constants
#define BB 256
#define SS 128
#define INPUT 256
#define PD 128
#define EE 64
#define INDIM 384     // INPUT + PD
#define RR 4
#define WW 64
#define RW 256        // RR*WW
#define MM 512
#define SHARDS 16

#define SC 8          // seq rows per block
#define TM 128        // mem tile rows
#define MST 68        // mem tile LDS row stride (floats), 16B aligned, pad vs 64

// LDS layout (float offsets)
#define OFF_PE 0
#define OFF_UE 128
#define OFF_C  192                  // SC*INDIM = 3072
#define OFF_Q  (192 + 3072)         // SC*RW = 2048
#define OFF_SC (3264 + 2048)        // SC*RR*MM = 16384 (also reused as q split-K partials)
#define OFF_MS (5312 + 16384)       // TM*MST = 8704
#define LDS_FLOATS (21696 + 8704)   // 30400
#define LDS_BYTES  (LDS_FLOATS * 4) // 121600 B

#define OUT1 8388608u               // B*S*R*W floats; final_state follows

__global__ void __launch_bounds__(256, 1)
fused_mem_access(const float* __restrict__ x,
                 const int*   __restrict__ user_id,
                 const float* __restrict__ uet,
                 const float* __restrict__ W_proc,
                 const float* __restrict__ b_proc,
                 const float* __restrict__ Wq,
                 const float* __restrict__ memG,
                 float* __restrict__ out)
{
    extern __shared__ float sm[];
    float* pe = sm + OFF_PE;
    float* ue = sm + OFF_UE;
    float* cs = sm + OFF_C;
    float* qs = sm + OFF_Q;
    float* sc = sm + OFF_SC;
    float* ms = sm + OFF_MS;

    const int b     = blockIdx.y;
    const int chunk = blockIdx.x;
    const int s0    = chunk * SC;
    const int t     = threadIdx.x;
    const int lane  = t & 63;
    const int wv    = t >> 6;   // wave id == r in score/read phases

    const int uid = user_id[b];
    const int sid = uid & (SHARDS - 1);
    const float* WqB  = Wq   + (size_t)sid * INDIM * RW;
    const float* memB = memG + (size_t)sid * MM * WW;

    // ---- P0: user embedding -> processed embedding (pe) ----
    if (t < EE) ue[t] = uet[(size_t)uid * EE + t];
    __syncthreads();
    if (t < PD) {
        float a = b_proc[t];
        #pragma unroll
        for (int e = 0; e < EE; ++e) a = fmaf(ue[e], W_proc[e * PD + t], a);
        pe[t] = a;
    }
    __syncthreads();

    // ---- P1: stage combined = [x | pe] for SC rows ----
    #pragma unroll
    for (int j = 0; j < SC; ++j)
        cs[j * INDIM + t] = x[(size_t)(b * SS + s0 + j) * INPUT + t];
    if (t < PD) {
        #pragma unroll
        for (int j = 0; j < SC; ++j)
            cs[j * INDIM + INPUT + t] = pe[t];
    }
    __syncthreads();

    // ---- P2: q = combined @ Wq  (split-K across 4 waves, 4 cols/thread) ----
    {
        float4 acc[SC];
        #pragma unroll
        for (int j = 0; j < SC; ++j) acc[j] = make_float4(0.f, 0.f, 0.f, 0.f);
        const int o0 = lane * 4;
        const int i0 = wv * 96;
        for (int i = i0; i < i0 + 96; i += 4) {
            float4 w0 = *(const float4*)&WqB[(size_t)(i + 0) * RW + o0];
            float4 w1 = *(const float4*)&WqB[(size_t)(i + 1) * RW + o0];
            float4 w2 = *(const float4*)&WqB[(size_t)(i + 2) * RW + o0];
            float4 w3 = *(const float4*)&WqB[(size_t)(i + 3) * RW + o0];
            #pragma unroll
            for (int j = 0; j < SC; ++j) {
                float4 a4 = *(const float4*)&cs[j * INDIM + i];
                acc[j].x = fmaf(a4.x, w0.x, acc[j].x); acc[j].y = fmaf(a4.x, w0.y, acc[j].y);
                acc[j].z = fmaf(a4.x, w0.z, acc[j].z); acc[j].w = fmaf(a4.x, w0.w, acc[j].w);
                acc[j].x = fmaf(a4.y, w1.x, acc[j].x); acc[j].y = fmaf(a4.y, w1.y, acc[j].y);
                acc[j].z = fmaf(a4.y, w1.z, acc[j].z); acc[j].w = fmaf(a4.y, w1.w, acc[j].w);
                acc[j].x = fmaf(a4.z, w2.x, acc[j].x); acc[j].y = fmaf(a4.z, w2.y, acc[j].y);
                acc[j].z = fmaf(a4.z, w2.z, acc[j].z); acc[j].w = fmaf(a4.z, w2.w, acc[j].w);
                acc[j].x = fmaf(a4.w, w3.x, acc[j].x); acc[j].y = fmaf(a4.w, w3.y, acc[j].y);
                acc[j].z = fmaf(a4.w, w3.z, acc[j].z); acc[j].w = fmaf(a4.w, w3.w, acc[j].w);
            }
        }
        // partials into sc scratch: [wave][j][col]
        #pragma unroll
        for (int j = 0; j < SC; ++j)
            *(float4*)&sc[(wv * SC + j) * RW + o0] = acc[j];
    }
    __syncthreads();
    #pragma unroll
    for (int j = 0; j < SC; ++j) {
        float v = sc[(0 * SC + j) * RW + t] + sc[(1 * SC + j) * RW + t]
                + sc[(2 * SC + j) * RW + t] + sc[(3 * SC + j) * RW + t];
        qs[j * RW + t] = v;
    }
    __syncthreads();

    // ---- P3: scores = q . mem^T  (4 tiles of 128 mem rows) ----
    for (int tile = 0; tile < 4; ++tile) {
        __syncthreads();   // prior tile compute done before overwriting ms
        #pragma unroll
        for (int k = 0; k < 8; ++k) {
            int fi = t * 4 + k * 1024;
            int ml = fi >> 6, w = fi & 63;
            *(float4*)&ms[ml * MST + w] = *(const float4*)&memB[tile * TM * WW + fi];
        }
        __syncthreads();
        float sa[SC], sb[SC];
        #pragma unroll
        for (int s = 0; s < SC; ++s) { sa[s] = 0.f; sb[s] = 0.f; }
        #pragma unroll
        for (int wb = 0; wb < 16; ++wb) {
            float4 ma = *(const float4*)&ms[lane * MST + wb * 4];
            float4 mb = *(const float4*)&ms[(lane + 64) * MST + wb * 4];
            #pragma unroll
            for (int s = 0; s < SC; ++s) {
                float4 q4 = *(const float4*)&qs[s * RW + wv * 64 + wb * 4];
                sa[s] += q4.x * ma.x + q4.y * ma.y + q4.z * ma.z + q4.w * ma.w;
                sb[s] += q4.x * mb.x + q4.y * mb.y + q4.z * mb.z + q4.w * mb.w;
            }
        }
        #pragma unroll
        for (int s = 0; s < SC; ++s) {
            sc[(s * 4 + wv) * MM + tile * TM + lane]      = sa[s];
            sc[(s * 4 + wv) * MM + tile * TM + 64 + lane] = sb[s];
        }
    }
    __syncthreads();

    // ---- P4: softmax over m per (s,r) row; emit final_state for b==B-1 ----
    #pragma unroll
    for (int k = 0; k < 8; ++k) {
        int ri = wv * 8 + k;          // ri = s_local*4 + r
        float4 v0 = *(float4*)&sc[ri * MM + lane * 4];
        float4 v1 = *(float4*)&sc[ri * MM + 256 + lane * 4];
        float mx = fmaxf(fmaxf(fmaxf(v0.x, v0.y), fmaxf(v0.z, v0.w)),
                         fmaxf(fmaxf(v1.x, v1.y), fmaxf(v1.z, v1.w)));
        for (int d = 32; d; d >>= 1) mx = fmaxf(mx, __shfl_xor(mx, d, 64));
        v0.x = expf(v0.x - mx); v0.y = expf(v0.y - mx);
        v0.z = expf(v0.z - mx); v0.w = expf(v0.w - mx);
        v1.x = expf(v1.x - mx); v1.y = expf(v1.y - mx);
        v1.z = expf(v1.z - mx); v1.w = expf(v1.w - mx);
        float sum = v0.x + v0.y + v0.z + v0.w + v1.x + v1.y + v1.z + v1.w;
        for (int d = 32; d; d >>= 1) sum += __shfl_xor(sum, d, 64);
        float inv = 1.0f / sum;
        v0.x *= inv; v0.y *= inv; v0.z *= inv; v0.w *= inv;
        v1.x *= inv; v1.y *= inv; v1.z *= inv; v1.w *= inv;
        *(float4*)&sc[ri * MM + lane * 4]       = v0;
        *(float4*)&sc[ri * MM + 256 + lane * 4] = v1;
        if (b == BB - 1) {
            size_t o2 = (size_t)OUT1 + ((size_t)(s0 + (ri >> 2)) * 4 + (ri & 3)) * MM;
            *(float4*)&out[o2 + lane * 4]       = v0;
            *(float4*)&out[o2 + 256 + lane * 4] = v1;
        }
    }

    // ---- P5: read = wts @ mem  (second pass over mem tiles) ----
    float racc[SC];
    #pragma unroll
    for (int s = 0; s < SC; ++s) racc[s] = 0.f;
    for (int tile = 0; tile < 4; ++tile) {
        __syncthreads();   // P4 writes (cross-wave) / prior tile compute done
        #pragma unroll
        for (int k = 0; k < 8; ++k) {
            int fi = t * 4 + k * 1024;
            int ml = fi >> 6, w = fi & 63;
            *(float4*)&ms[ml * MST + w] = *(const float4*)&memB[tile * TM * WW + fi];
        }
        __syncthreads();
        #pragma unroll
        for (int mq = 0; mq < 32; ++mq) {
            float m0 = ms[(mq * 4 + 0) * MST + lane];
            float m1 = ms[(mq * 4 + 1) * MST + lane];
            float m2 = ms[(mq * 4 + 2) * MST + lane];
            float m3 = ms[(mq * 4 + 3) * MST + lane];
            #pragma unroll
            for (int s = 0; s < SC; ++s) {
                float4 w4 = *(const float4*)&sc[(s * 4 + wv) * MM + tile * TM + mq * 4];
                racc[s] += w4.x * m0 + w4.y * m1 + w4.z * m2 + w4.w * m3;
            }
        }
    }
    #pragma unroll
    for (int s = 0; s < SC; ++s)
        out[((size_t)((b * SS + s0 + s) * 4 + wv)) * WW + lane] = racc[s];
}

extern "C" void kernel_launch(void* const* d_in, const int* in_sizes, int n_in,
                              void* d_out, int out_size, void* d_ws, size_t ws_size,
                              hipStream_t stream) {
    const float* x    = (const float*)d_in[0];
    const int*   uid  = (const int*)  d_in[1];
    const float* uet  = (const float*)d_in[2];
    const float* Wp   = (const float*)d_in[3];
    const float* bp   = (const float*)d_in[4];
    const float* Wq   = (const float*)d_in[5];
    const float* mem  = (const float*)d_in[6];
    float* out = (float*)d_out;

    // opt-in to >64KB dynamic LDS (idempotent, host-side, capture-safe)
    hipFuncSetAttribute((const void*)fused_mem_access,
                        hipFuncAttributeMaxDynamicSharedMemorySize, LDS_BYTES);

    dim3 grid(SS / SC, BB);
    fused_mem_access<<<grid, 256, LDS_BYTES, stream>>>(x, uid, uet, Wp, bp, Wq, mem, out);
}

// Round 4
// 198.026 us; speedup vs baseline: 6.6653x; 6.6653x over previous
//
#include <hip/hip_runtime.h>
#include <math.h>

#define BB 256
#define SSEQ 128
#define INPUT 256
#define PD 128
#define EE 64
#define RW 256
#define MM 512
#define WW 64
#define KD 384          // IN_DIM

typedef _Float16 half8 __attribute__((ext_vector_type(8)));
typedef __fp16 fp16x2 __attribute__((ext_vector_type(2)));
typedef float float4v __attribute__((ext_vector_type(4)));

#define LOG2E 1.44269504088896f
#define OUT1 8388608u

// LDS byte layout
#define MEMT_OFF 65536            // memT f16 [64 w][512 m], row 1024B, 16B-chunk XOR swizzle
#define F32_OFF  131072           // small f32 scratch
#define LDS_BYTES (131072 + 3840)
// f32 scratch float-offsets
#define UE_O 0
#define PE_O 64
#define QPE_O 192
#define QP_O 448                  // qpart [512]

union H8 { half8 h8; unsigned int u[4]; uint4 u4; };

__device__ __forceinline__ unsigned int pk2(float a, float b) {
    union { fp16x2 h; unsigned int u; } p;
    p.h = __builtin_amdgcn_cvt_pkrtz(a, b);
    return p.u;
}

// ---------- kernel 0: WqT[sid][n][k] = f16(Wq[sid][k][n]) ----------
__global__ void wqt_kernel(const float* __restrict__ Wq, _Float16* __restrict__ WqT) {
    __shared__ float tile[64][65];
    const int kt = blockIdx.x, nt = blockIdx.y, sid = blockIdx.z;
    const float* src = Wq + (size_t)sid*KD*RW + (size_t)(kt*64)*RW + nt*64;
    for (int i = 0; i < 16; ++i) {
        int idx = i*256 + threadIdx.x;
        int kk = idx >> 6, nn = idx & 63;
        tile[kk][nn] = src[(size_t)kk*RW + nn];
    }
    __syncthreads();
    _Float16* dst = WqT + (size_t)sid*RW*KD + (size_t)(nt*64)*KD + kt*64;
    for (int i = 0; i < 16; ++i) {
        int idx = i*256 + threadIdx.x;
        int nn = idx >> 6, kk = idx & 63;
        dst[(size_t)nn*KD + kk] = (_Float16)tile[kk][nn];
    }
}

// ---------- main fused kernel ----------
__global__ void __launch_bounds__(512, 2)
attn_kernel(const float* __restrict__ x, const int* __restrict__ user_id,
            const float* __restrict__ uet, const float* __restrict__ W_proc,
            const float* __restrict__ b_proc, const float* __restrict__ Wq,
            const float* __restrict__ memG, const _Float16* __restrict__ WqT,
            int useWqT, float* __restrict__ out)
{
    extern __shared__ char smraw[];
    unsigned short* smemu = (unsigned short*)smraw;
    uint4* sm128 = (uint4*)smraw;
    float* smf = (float*)(smraw + F32_OFF);

    const int t = threadIdx.x;
    const int b = blockIdx.x;
    const int halfb = blockIdx.y;
    const int lane = t & 63, wv = t >> 6;
    const int n16 = lane & 15, quad = lane >> 4;
    const int r = wv & 3, sq = wv >> 2;
    const int s0 = halfb*64 + sq*32;
    const int swz = n16 & 7;

    const int uid = user_id[b];
    const int sid = uid & 15;
    const float* memB = memG + (size_t)sid * (MM*WW);

    if (t < EE) smf[UE_O + t] = uet[(size_t)uid*EE + t];

    // stage mem -> LDS f16, row 128B, chunk swizzle c' = c ^ (m&7)
    for (int i = 0; i < 8; ++i) {
        int id = t + i*512;                  // 16B-chunk id, 0..4095
        int m = id >> 3, cw = id & 7;
        const float* g = memB + m*64 + cw*8;
        float4 a0 = *(const float4*)g;
        float4 a1 = *(const float4*)(g + 4);
        int c2 = cw ^ (m & 7);
        sm128[(m*128 + (c2<<4)) >> 4] =
            make_uint4(pk2(a0.x,a0.y), pk2(a0.z,a0.w), pk2(a1.x,a1.y), pk2(a1.z,a1.w));
    }
    __syncthreads();

    // memT[w][m] via LDS readback transpose (u16 reads conflict-free, b128 writes linear-equiv)
    for (int i = 0; i < 8; ++i) {
        int id = t + i*512;
        int w = id & 63, cm = id >> 6;       // cm: m-chunk 0..63
        unsigned int uu[4];
        #pragma unroll
        for (int p = 0; p < 4; ++p) {
            int m0 = cm*8 + 2*p, m1 = m0 + 1;
            unsigned short lo = smemu[m0*64 + (((w>>3) ^ (m0&7))<<3) + (w&7)];
            unsigned short hi = smemu[m1*64 + (((w>>3) ^ (m1&7))<<3) + (w&7)];
            uu[p] = (unsigned int)lo | ((unsigned int)hi << 16);
        }
        sm128[(MEMT_OFF + w*1024 + ((cm ^ (w&7))<<4)) >> 4] = make_uint4(uu[0],uu[1],uu[2],uu[3]);
    }
    // pe (needs ue; memT readback above doesn't conflict)
    if (t < PD) {
        float a = b_proc[t];
        #pragma unroll
        for (int e = 0; e < EE; ++e) a = fmaf(smf[UE_O + e], W_proc[e*PD + t], a);
        smf[PE_O + t] = a;
    }
    __syncthreads();
    // qpe partials: qpe[n] = sum_k pe[k] * Wq[256+k][n]
    {
        int n = t & 255, h = t >> 8;
        float s = 0.f;
        const float* wr = Wq + (size_t)sid*KD*RW + (size_t)(256 + h*64)*RW + n;
        #pragma unroll 8
        for (int k = 0; k < 64; ++k) s = fmaf(smf[PE_O + h*64 + k], wr[(size_t)k*RW], s);
        smf[QP_O + h*256 + n] = s;
    }
    __syncthreads();
    if (t < 256) smf[QPE_O + t] = LOG2E * (smf[QP_O + t] + smf[QP_O + 256 + t]);
    __syncthreads();

    // ================= per-wave, no more barriers =================

    // ---- Phase Q: qT[n][s] over the x-part only (k = 0..255); pe-part enters
    //      via the qpe bias. kc MUST stop at 8: kc>=8 would read past x rows
    //      (and past the x allocation for the last rows) -> page fault + wrong q.
    float4v qacc[4][2];
    #pragma unroll
    for (int mt = 0; mt < 4; ++mt)
        #pragma unroll
        for (int nt = 0; nt < 2; ++nt) qacc[mt][nt] = (float4v)0.f;

    const float* xB = x + (size_t)(b*SSEQ + s0) * INPUT;
    for (int kc = 0; kc < 8; ++kc) {
        H8 afr[4];
        if (useWqT) {
            const _Float16* wt0 = WqT + (size_t)sid*RW*KD + (size_t)(r*64)*KD + kc*32 + quad*8;
            #pragma unroll
            for (int mt = 0; mt < 4; ++mt)
                afr[mt].u4 = *(const uint4*)(wt0 + (size_t)(mt*16 + n16)*KD);
        } else {
            const float* wq0 = Wq + (size_t)sid*KD*RW + (size_t)(kc*32 + quad*8)*RW + r*64 + n16;
            #pragma unroll
            for (int mt = 0; mt < 4; ++mt)
                #pragma unroll
                for (int p = 0; p < 4; ++p)
                    afr[mt].u[p] = pk2(wq0[(size_t)(2*p)*RW + mt*16],
                                       wq0[(size_t)(2*p+1)*RW + mt*16]);
        }
        H8 bfr[2];
        #pragma unroll
        for (int nt = 0; nt < 2; ++nt) {
            const float* xg = xB + (size_t)(nt*16 + n16)*INPUT + kc*32 + quad*8;
            float4 a0 = *(const float4*)xg;
            float4 a1 = *(const float4*)(xg + 4);
            bfr[nt].u[0] = pk2(a0.x*LOG2E, a0.y*LOG2E);
            bfr[nt].u[1] = pk2(a0.z*LOG2E, a0.w*LOG2E);
            bfr[nt].u[2] = pk2(a1.x*LOG2E, a1.y*LOG2E);
            bfr[nt].u[3] = pk2(a1.z*LOG2E, a1.w*LOG2E);
        }
        #pragma unroll
        for (int mt = 0; mt < 4; ++mt)
            #pragma unroll
            for (int nt = 0; nt < 2; ++nt)
                qacc[mt][nt] = __builtin_amdgcn_mfma_f32_16x16x32_f16(afr[mt].h8, bfr[nt].h8, qacc[mt][nt], 0, 0, 0);
    }
    // + qpe (already *log2e), rows n = r*64 + mt*16 + quad*4 + reg
    #pragma unroll
    for (int mt = 0; mt < 4; ++mt)
        #pragma unroll
        for (int reg = 0; reg < 4; ++reg) {
            float qv = smf[QPE_O + r*64 + mt*16 + quad*4 + reg];
            #pragma unroll
            for (int nt = 0; nt < 2; ++nt) qacc[mt][nt][reg] += qv;
        }
    // pack qT to f16 pairs, then repack (shuffles) into scores-B fragments
    unsigned int pkq[4][2][2];
    #pragma unroll
    for (int mt = 0; mt < 4; ++mt)
        #pragma unroll
        for (int nt = 0; nt < 2; ++nt) {
            pkq[mt][nt][0] = pk2(qacc[mt][nt][0], qacc[mt][nt][1]);
            pkq[mt][nt][1] = pk2(qacc[mt][nt][2], qacc[mt][nt][3]);
        }
    unsigned int bq[2][2][4];
    #pragma unroll
    for (int kc2 = 0; kc2 < 2; ++kc2)
        #pragma unroll
        for (int nt = 0; nt < 2; ++nt)
            #pragma unroll
            for (int p = 0; p < 4; ++p) {
                int qp = ((quad & 1) << 1) | (p >> 1);
                int src = n16 + (qp << 4);
                int sr = p & 1;
                int lo  = __shfl((int)pkq[kc2*2    ][nt][sr], src, 64);
                int hiv = __shfl((int)pkq[kc2*2 + 1][nt][sr], src, 64);
                bq[kc2][nt][p] = (unsigned int)((quad < 2) ? lo : hiv);
            }

    // ---- main flash loop over 16 m-tiles of 32 ----
    float4v Oa[4][2];
    #pragma unroll
    for (int wt = 0; wt < 4; ++wt)
        #pragma unroll
        for (int nt = 0; nt < 2; ++nt) Oa[wt][nt] = (float4v)0.f;
    float Ml[2] = {-1e30f, -1e30f}, ll[2] = {0.f, 0.f};

    for (int mtile = 0; mtile < 16; ++mtile) {
        float4v Sa[2][2];
        #pragma unroll
        for (int msub = 0; msub < 2; ++msub)
            #pragma unroll
            for (int nt = 0; nt < 2; ++nt) Sa[msub][nt] = (float4v)0.f;
        #pragma unroll
        for (int msub = 0; msub < 2; ++msub) {
            int m = mtile*32 + msub*16 + n16;
            #pragma unroll
            for (int kc2 = 0; kc2 < 2; ++kc2) {
                H8 af; af.u4 = sm128[(m*128 + (((kc2*4 + quad) ^ swz) << 4)) >> 4];
                #pragma unroll
                for (int nt = 0; nt < 2; ++nt) {
                    H8 bf; bf.u[0]=bq[kc2][nt][0]; bf.u[1]=bq[kc2][nt][1];
                           bf.u[2]=bq[kc2][nt][2]; bf.u[3]=bq[kc2][nt][3];
                    Sa[msub][nt] = __builtin_amdgcn_mfma_f32_16x16x32_f16(af.h8, bf.h8, Sa[msub][nt], 0, 0, 0);
                }
            }
        }
        unsigned int pkP[2][2][2];
        #pragma unroll
        for (int nt = 0; nt < 2; ++nt) {
            float tm = Sa[0][nt][0];
            #pragma unroll
            for (int g = 1; g < 4; ++g) tm = fmaxf(tm, Sa[0][nt][g]);
            #pragma unroll
            for (int g = 0; g < 4; ++g) tm = fmaxf(tm, Sa[1][nt][g]);
            tm = fmaxf(tm, __shfl_xor(tm, 16, 64));
            tm = fmaxf(tm, __shfl_xor(tm, 32, 64));
            float Mn = fmaxf(Ml[nt], tm);
            float al = __builtin_amdgcn_exp2f(Ml[nt] - Mn);
            float pv[2][4]; float ts = 0.f;
            #pragma unroll
            for (int msub = 0; msub < 2; ++msub)
                #pragma unroll
                for (int g = 0; g < 4; ++g) {
                    pv[msub][g] = __builtin_amdgcn_exp2f(Sa[msub][nt][g] - Mn);
                    ts += pv[msub][g];
                }
            ts += __shfl_xor(ts, 16, 64);
            ts += __shfl_xor(ts, 32, 64);
            ll[nt] = al*ll[nt] + ts;
            Ml[nt] = Mn;
            pkP[0][nt][0] = pk2(pv[0][0], pv[0][1]); pkP[0][nt][1] = pk2(pv[0][2], pv[0][3]);
            pkP[1][nt][0] = pk2(pv[1][0], pv[1][1]); pkP[1][nt][1] = pk2(pv[1][2], pv[1][3]);
            #pragma unroll
            for (int wt = 0; wt < 4; ++wt)
                #pragma unroll
                for (int g = 0; g < 4; ++g) Oa[wt][nt][g] *= al;
        }
        unsigned int bp[2][4];
        #pragma unroll
        for (int nt = 0; nt < 2; ++nt)
            #pragma unroll
            for (int p = 0; p < 4; ++p) {
                int qp = ((quad & 1) << 1) | (p >> 1);
                int src = n16 + (qp << 4);
                int sr = p & 1;
                int lo  = __shfl((int)pkP[0][nt][sr], src, 64);
                int hiv = __shfl((int)pkP[1][nt][sr], src, 64);
                bp[nt][p] = (unsigned int)((quad < 2) ? lo : hiv);
            }
        #pragma unroll
        for (int wt = 0; wt < 4; ++wt) {
            H8 af; af.u4 = sm128[(MEMT_OFF + (wt*16 + n16)*1024 + (((mtile*4 + quad) ^ swz) << 4)) >> 4];
            #pragma unroll
            for (int nt = 0; nt < 2; ++nt) {
                H8 bf; bf.u[0]=bp[nt][0]; bf.u[1]=bp[nt][1]; bf.u[2]=bp[nt][2]; bf.u[3]=bp[nt][3];
                Oa[wt][nt] = __builtin_amdgcn_mfma_f32_16x16x32_f16(af.h8, bf.h8, Oa[wt][nt], 0, 0, 0);
            }
        }
    }

    // ---- store read_words ----
    #pragma unroll
    for (int nt = 0; nt < 2; ++nt) {
        float inv = 1.0f / ll[nt];
        int s = s0 + nt*16 + n16;
        #pragma unroll
        for (int wt = 0; wt < 4; ++wt) {
            float4 o = make_float4(Oa[wt][nt][0]*inv, Oa[wt][nt][1]*inv,
                                   Oa[wt][nt][2]*inv, Oa[wt][nt][3]*inv);
            *(float4*)&out[((size_t)(b*SSEQ + s)*4 + r)*WW + wt*16 + quad*4] = o;
        }
    }

    // ---- final_state (b == 255): recompute scores, store normalized wts ----
    if (b == BB - 1) {
        for (int mtile = 0; mtile < 16; ++mtile) {
            float4v Sa[2][2];
            #pragma unroll
            for (int msub = 0; msub < 2; ++msub)
                #pragma unroll
                for (int nt = 0; nt < 2; ++nt) Sa[msub][nt] = (float4v)0.f;
            #pragma unroll
            for (int msub = 0; msub < 2; ++msub) {
                int m = mtile*32 + msub*16 + n16;
                #pragma unroll
                for (int kc2 = 0; kc2 < 2; ++kc2) {
                    H8 af; af.u4 = sm128[(m*128 + (((kc2*4 + quad) ^ swz) << 4)) >> 4];
                    #pragma unroll
                    for (int nt = 0; nt < 2; ++nt) {
                        H8 bf; bf.u[0]=bq[kc2][nt][0]; bf.u[1]=bq[kc2][nt][1];
                               bf.u[2]=bq[kc2][nt][2]; bf.u[3]=bq[kc2][nt][3];
                        Sa[msub][nt] = __builtin_amdgcn_mfma_f32_16x16x32_f16(af.h8, bf.h8, Sa[msub][nt], 0, 0, 0);
                    }
                }
            }
            #pragma unroll
            for (int nt = 0; nt < 2; ++nt) {
                float inv = 1.0f / ll[nt];
                int s = s0 + nt*16 + n16;
                size_t base = (size_t)OUT1 + ((size_t)(s*4 + r) << 9);
                #pragma unroll
                for (int msub = 0; msub < 2; ++msub) {
                    float4 w4 = make_float4(
                        __builtin_amdgcn_exp2f(Sa[msub][nt][0] - Ml[nt]) * inv,
                        __builtin_amdgcn_exp2f(Sa[msub][nt][1] - Ml[nt]) * inv,
                        __builtin_amdgcn_exp2f(Sa[msub][nt][2] - Ml[nt]) * inv,
                        __builtin_amdgcn_exp2f(Sa[msub][nt][3] - Ml[nt]) * inv);
                    *(float4*)&out[base + mtile*32 + msub*16 + quad*4] = w4;
                }
            }
        }
    }
}

extern "C" void kernel_launch(void* const* d_in, const int* in_sizes, int n_in,
                              void* d_out, int out_size, void* d_ws, size_t ws_size,
                              hipStream_t stream) {
    const float* x    = (const float*)d_in[0];
    const int*   uid  = (const int*)  d_in[1];
    const float* uet  = (const float*)d_in[2];
    const float* Wp   = (const float*)d_in[3];
    const float* bp   = (const float*)d_in[4];
    const float* Wq   = (const float*)d_in[5];
    const float* mem  = (const float*)d_in[6];
    float* out = (float*)d_out;

    const size_t need = (size_t)16 * RW * KD * 2;   // WqT f16
    int useWqT = (ws_size >= need) ? 1 : 0;
    _Float16* WqT = (_Float16*)d_ws;

    if (useWqT) {
        dim3 g0(KD/64, RW/64, 16);
        wqt_kernel<<<g0, 256, 0, stream>>>(Wq, WqT);
    }

    (void)hipFuncSetAttribute((const void*)attn_kernel,
                              hipFuncAttributeMaxDynamicSharedMemorySize, LDS_BYTES);
    dim3 grid(BB, 2);
    attn_kernel<<<grid, 512, LDS_BYTES, stream>>>(x, uid, uet, Wp, bp, Wq, mem, WqT, useWqT, out);
}

// Round 5
// 175.171 us; speedup vs baseline: 7.5349x; 1.1305x over previous
//
#include <hip/hip_runtime.h>
#include <math.h>

#define BB 256
#define SSEQ 128
#define INPUT 256
#define PD 128
#define EE 64
#define RW 256
#define MM 512
#define WW 64
#define KD 384          // IN_DIM

typedef _Float16 half8 __attribute__((ext_vector_type(8)));
typedef __fp16 fp16x2 __attribute__((ext_vector_type(2)));
typedef float float4v __attribute__((ext_vector_type(4)));

#define LOG2E 1.44269504088896f
#define OUT1 8388608u

// attn LDS byte layout: [0,64K) mem f16 swizzled, [64K,128K) memT f16 swizzled, f32 scratch after
#define MEMT_OFF 65536
#define F32_OFF  131072
#define LDS_BYTES (131072 + 6144)
// f32 scratch float-offsets
#define UE_O 0
#define PE_O 64
#define QPE_O 192
#define QP_O 448                  // qpart [1024]

// workspace layout: [0,2M) per-shard LDS images (128KB each), [2M, 2M+3.1M) WqT f16
#define IMG_SHARD 131072
#define WQT_OFF  (16*IMG_SHARD)
#define WQT_BYTES ((size_t)16*RW*KD*2)
#define PREP_LDS 65536

union H8 { half8 h8; unsigned int u[4]; uint4 u4; };

__device__ __forceinline__ unsigned int pk2(float a, float b) {
    union { fp16x2 h; unsigned int u; } p;
    p.h = __builtin_amdgcn_cvt_pkrtz(a, b);
    return p.u;
}

// ---------- prep kernel: blocks 0..383 build WqT; 384..399 build mem LDS-images ----------
__global__ void prep_kernel(const float* __restrict__ Wq, const float* __restrict__ memG,
                            char* __restrict__ ws, int useImg, int useWqT) {
    extern __shared__ char sm[];
    const int blk = blockIdx.x;
    const int t = threadIdx.x;
    if (blk < 384) {
        if (!useWqT) return;
        // WqT[sid][n][k] = f16(Wq[sid][k][n])
        float (*tile)[65] = (float (*)[65])sm;
        const int kt = blk % 6, ntb = (blk / 6) & 3, sid = blk / 24;
        const float* src = Wq + (size_t)sid*KD*RW + (size_t)(kt*64)*RW + ntb*64;
        for (int i = 0; i < 16; ++i) {
            int idx = i*256 + t;
            int kk = idx >> 6, nn = idx & 63;
            tile[kk][nn] = src[(size_t)kk*RW + nn];
        }
        __syncthreads();
        _Float16* dst = (_Float16*)(ws + WQT_OFF) + (size_t)sid*RW*KD + (size_t)(ntb*64)*KD + kt*64;
        for (int i = 0; i < 16; ++i) {
            int idx = i*256 + t;
            int nn = idx >> 6, kk = idx & 63;
            dst[(size_t)nn*KD + kk] = (_Float16)tile[kk][nn];
        }
    } else {
        if (!useImg) return;
        // per-shard pre-swizzled f16 images: A (mem rows) + B (memT), exactly the attn LDS layout
        const int sid = blk - 384;
        const float* memB = memG + (size_t)sid * (MM*WW);
        uint4* lds128 = (uint4*)sm;
        unsigned short* ldsu = (unsigned short*)sm;
        uint4* wsA = (uint4*)(ws + (size_t)sid*IMG_SHARD);
        uint4* wsB = wsA + 4096;
        // phase 1: f32 -> f16, image A (chunk = m*8 + (c^(m&7))), also stash in LDS same layout
        for (int i = 0; i < 16; ++i) {
            int id = i*256 + t;              // 0..4095
            int m = id >> 3, cw = id & 7;
            const float* g = memB + m*64 + cw*8;
            float4 a0 = *(const float4*)g;
            float4 a1 = *(const float4*)(g + 4);
            uint4 v = make_uint4(pk2(a0.x,a0.y), pk2(a0.z,a0.w), pk2(a1.x,a1.y), pk2(a1.z,a1.w));
            int chunk = m*8 + (cw ^ (m & 7));
            lds128[chunk] = v;
            wsA[chunk] = v;
        }
        __syncthreads();
        // phase 2: transpose via LDS u16 gathers -> image B (chunk = w*64 + (cm^(w&7)))
        for (int i = 0; i < 16; ++i) {
            int id = i*256 + t;
            int w = id & 63, cm = id >> 6;
            unsigned int uu[4];
            #pragma unroll
            for (int p = 0; p < 4; ++p) {
                int m0 = cm*8 + 2*p, m1 = m0 + 1;
                unsigned short lo = ldsu[m0*64 + (((w>>3) ^ (m0&7))<<3) + (w&7)];
                unsigned short hi = ldsu[m1*64 + (((w>>3) ^ (m1&7))<<3) + (w&7)];
                uu[p] = (unsigned int)lo | ((unsigned int)hi << 16);
            }
            wsB[w*64 + (cm ^ (w & 7))] = make_uint4(uu[0], uu[1], uu[2], uu[3]);
        }
    }
}

// ---------- main fused kernel: 256 blocks x 1024 threads (16 waves) ----------
__global__ void __launch_bounds__(1024, 4)
attn_kernel(const float* __restrict__ x, const int* __restrict__ user_id,
            const float* __restrict__ uet, const float* __restrict__ W_proc,
            const float* __restrict__ b_proc, const float* __restrict__ Wq,
            const float* __restrict__ memG, const char* __restrict__ ws,
            int useImg, int useWqT, float* __restrict__ out)
{
    extern __shared__ char smraw[];
    unsigned short* smemu = (unsigned short*)smraw;
    uint4* sm128 = (uint4*)smraw;
    float* smf = (float*)(smraw + F32_OFF);

    const int t = threadIdx.x;
    const int b = blockIdx.x;
    const int lane = t & 63, wv = t >> 6;        // 16 waves
    const int n16 = lane & 15, quad = lane >> 4;
    const int r = wv & 3, sq = wv >> 2;          // sq 0..3
    const int s0 = sq * 32;
    const int swz = n16 & 7;

    const int uid = user_id[b];
    const int sid = uid & 15;
    const float* memB = memG + (size_t)sid * (MM*WW);

    if (t < EE) smf[UE_O + t] = uet[(size_t)uid*EE + t];

    if (useImg) {
        // pure linear copy of the pre-swizzled 128 KB image (L2-resident)
        const uint4* img = (const uint4*)(ws + (size_t)sid*IMG_SHARD);
        #pragma unroll
        for (int i = 0; i < 8; ++i) {
            int id = i*1024 + t;                 // 0..8191
            sm128[id] = img[id];
        }
    } else {
        // fallback: in-block convert + transpose (R4 path, 1024-thread indexing)
        for (int i = 0; i < 4; ++i) {
            int id = t + i*1024;                 // 0..4095
            int m = id >> 3, cw = id & 7;
            const float* g = memB + m*64 + cw*8;
            float4 a0 = *(const float4*)g;
            float4 a1 = *(const float4*)(g + 4);
            sm128[m*8 + (cw ^ (m & 7))] =
                make_uint4(pk2(a0.x,a0.y), pk2(a0.z,a0.w), pk2(a1.x,a1.y), pk2(a1.z,a1.w));
        }
        __syncthreads();
        for (int i = 0; i < 4; ++i) {
            int id = t + i*1024;
            int w = id & 63, cm = id >> 6;
            unsigned int uu[4];
            #pragma unroll
            for (int p = 0; p < 4; ++p) {
                int m0 = cm*8 + 2*p, m1 = m0 + 1;
                unsigned short lo = smemu[m0*64 + (((w>>3) ^ (m0&7))<<3) + (w&7)];
                unsigned short hi = smemu[m1*64 + (((w>>3) ^ (m1&7))<<3) + (w&7)];
                uu[p] = (unsigned int)lo | ((unsigned int)hi << 16);
            }
            sm128[(MEMT_OFF >> 4) + w*64 + (cm ^ (w & 7))] = make_uint4(uu[0],uu[1],uu[2],uu[3]);
        }
    }
    __syncthreads();
    // pe
    if (t < PD) {
        float a = b_proc[t];
        #pragma unroll
        for (int e = 0; e < EE; ++e) a = fmaf(smf[UE_O + e], W_proc[e*PD + t], a);
        smf[PE_O + t] = a;
    }
    __syncthreads();
    // qpe partials: qpe[n] = sum_k pe[k] * Wq[256+k][n], 4-way k-split
    {
        int n = t & 255, h = t >> 8;             // h 0..3
        float s = 0.f;
        const float* wr = Wq + (size_t)sid*KD*RW + (size_t)(256 + h*32)*RW + n;
        #pragma unroll 8
        for (int k = 0; k < 32; ++k) s = fmaf(smf[PE_O + h*32 + k], wr[(size_t)k*RW], s);
        smf[QP_O + h*256 + n] = s;
    }
    __syncthreads();
    if (t < 256) smf[QPE_O + t] = LOG2E * (smf[QP_O + t] + smf[QP_O + 256 + t]
                                         + smf[QP_O + 512 + t] + smf[QP_O + 768 + t]);
    __syncthreads();

    // ================= per-wave, no more barriers =================

    // Phase Q over the x-part only (k = 0..255); pe-part enters via qpe bias.
    // kc MUST stop at 8 (x rows are 256 wide).
    float4v qacc[4][2];
    #pragma unroll
    for (int mt = 0; mt < 4; ++mt)
        #pragma unroll
        for (int nt = 0; nt < 2; ++nt) qacc[mt][nt] = (float4v)0.f;

    const float* xB = x + (size_t)(b*SSEQ + s0) * INPUT;
    for (int kc = 0; kc < 8; ++kc) {
        H8 afr[4];
        if (useWqT) {
            const _Float16* wt0 = (const _Float16*)(ws + WQT_OFF)
                                + (size_t)sid*RW*KD + (size_t)(r*64)*KD + kc*32 + quad*8;
            #pragma unroll
            for (int mt = 0; mt < 4; ++mt)
                afr[mt].u4 = *(const uint4*)(wt0 + (size_t)(mt*16 + n16)*KD);
        } else {
            const float* wq0 = Wq + (size_t)sid*KD*RW + (size_t)(kc*32 + quad*8)*RW + r*64 + n16;
            #pragma unroll
            for (int mt = 0; mt < 4; ++mt)
                #pragma unroll
                for (int p = 0; p < 4; ++p)
                    afr[mt].u[p] = pk2(wq0[(size_t)(2*p)*RW + mt*16],
                                       wq0[(size_t)(2*p+1)*RW + mt*16]);
        }
        H8 bfr[2];
        #pragma unroll
        for (int nt = 0; nt < 2; ++nt) {
            const float* xg = xB + (size_t)(nt*16 + n16)*INPUT + kc*32 + quad*8;
            float4 a0 = *(const float4*)xg;
            float4 a1 = *(const float4*)(xg + 4);
            bfr[nt].u[0] = pk2(a0.x*LOG2E, a0.y*LOG2E);
            bfr[nt].u[1] = pk2(a0.z*LOG2E, a0.w*LOG2E);
            bfr[nt].u[2] = pk2(a1.x*LOG2E, a1.y*LOG2E);
            bfr[nt].u[3] = pk2(a1.z*LOG2E, a1.w*LOG2E);
        }
        #pragma unroll
        for (int mt = 0; mt < 4; ++mt)
            #pragma unroll
            for (int nt = 0; nt < 2; ++nt)
                qacc[mt][nt] = __builtin_amdgcn_mfma_f32_16x16x32_f16(afr[mt].h8, bfr[nt].h8, qacc[mt][nt], 0, 0, 0);
    }
    #pragma unroll
    for (int mt = 0; mt < 4; ++mt)
        #pragma unroll
        for (int reg = 0; reg < 4; ++reg) {
            float qv = smf[QPE_O + r*64 + mt*16 + quad*4 + reg];
            #pragma unroll
            for (int nt = 0; nt < 2; ++nt) qacc[mt][nt][reg] += qv;
        }
    unsigned int pkq[4][2][2];
    #pragma unroll
    for (int mt = 0; mt < 4; ++mt)
        #pragma unroll
        for (int nt = 0; nt < 2; ++nt) {
            pkq[mt][nt][0] = pk2(qacc[mt][nt][0], qacc[mt][nt][1]);
            pkq[mt][nt][1] = pk2(qacc[mt][nt][2], qacc[mt][nt][3]);
        }
    unsigned int bq[2][2][4];
    #pragma unroll
    for (int kc2 = 0; kc2 < 2; ++kc2)
        #pragma unroll
        for (int nt = 0; nt < 2; ++nt)
            #pragma unroll
            for (int p = 0; p < 4; ++p) {
                int qp = ((quad & 1) << 1) | (p >> 1);
                int src = n16 + (qp << 4);
                int sr = p & 1;
                int lo  = __shfl((int)pkq[kc2*2    ][nt][sr], src, 64);
                int hiv = __shfl((int)pkq[kc2*2 + 1][nt][sr], src, 64);
                bq[kc2][nt][p] = (unsigned int)((quad < 2) ? lo : hiv);
            }

    // ---- main flash loop over 16 m-tiles of 32 ----
    float4v Oa[4][2];
    #pragma unroll
    for (int wt = 0; wt < 4; ++wt)
        #pragma unroll
        for (int nt = 0; nt < 2; ++nt) Oa[wt][nt] = (float4v)0.f;
    float Ml[2] = {-1e30f, -1e30f}, ll[2] = {0.f, 0.f};

    for (int mtile = 0; mtile < 16; ++mtile) {
        float4v Sa[2][2];
        #pragma unroll
        for (int msub = 0; msub < 2; ++msub)
            #pragma unroll
            for (int nt = 0; nt < 2; ++nt) Sa[msub][nt] = (float4v)0.f;
        #pragma unroll
        for (int msub = 0; msub < 2; ++msub) {
            int m = mtile*32 + msub*16 + n16;
            #pragma unroll
            for (int kc2 = 0; kc2 < 2; ++kc2) {
                H8 af; af.u4 = sm128[m*8 + ((kc2*4 + quad) ^ swz)];
                #pragma unroll
                for (int nt = 0; nt < 2; ++nt) {
                    H8 bf; bf.u[0]=bq[kc2][nt][0]; bf.u[1]=bq[kc2][nt][1];
                           bf.u[2]=bq[kc2][nt][2]; bf.u[3]=bq[kc2][nt][3];
                    Sa[msub][nt] = __builtin_amdgcn_mfma_f32_16x16x32_f16(af.h8, bf.h8, Sa[msub][nt], 0, 0, 0);
                }
            }
        }
        unsigned int pkP[2][2][2];
        #pragma unroll
        for (int nt = 0; nt < 2; ++nt) {
            float tm = Sa[0][nt][0];
            #pragma unroll
            for (int g = 1; g < 4; ++g) tm = fmaxf(tm, Sa[0][nt][g]);
            #pragma unroll
            for (int g = 0; g < 4; ++g) tm = fmaxf(tm, Sa[1][nt][g]);
            tm = fmaxf(tm, __shfl_xor(tm, 16, 64));
            tm = fmaxf(tm, __shfl_xor(tm, 32, 64));
            float Mn = fmaxf(Ml[nt], tm);
            float al = __builtin_amdgcn_exp2f(Ml[nt] - Mn);
            float pv[2][4]; float ts = 0.f;
            #pragma unroll
            for (int msub = 0; msub < 2; ++msub)
                #pragma unroll
                for (int g = 0; g < 4; ++g) {
                    pv[msub][g] = __builtin_amdgcn_exp2f(Sa[msub][nt][g] - Mn);
                    ts += pv[msub][g];
                }
            ts += __shfl_xor(ts, 16, 64);
            ts += __shfl_xor(ts, 32, 64);
            ll[nt] = al*ll[nt] + ts;
            Ml[nt] = Mn;
            pkP[0][nt][0] = pk2(pv[0][0], pv[0][1]); pkP[0][nt][1] = pk2(pv[0][2], pv[0][3]);
            pkP[1][nt][0] = pk2(pv[1][0], pv[1][1]); pkP[1][nt][1] = pk2(pv[1][2], pv[1][3]);
            #pragma unroll
            for (int wt = 0; wt < 4; ++wt)
                #pragma unroll
                for (int g = 0; g < 4; ++g) Oa[wt][nt][g] *= al;
        }
        unsigned int bp[2][4];
        #pragma unroll
        for (int nt = 0; nt < 2; ++nt)
            #pragma unroll
            for (int p = 0; p < 4; ++p) {
                int qp = ((quad & 1) << 1) | (p >> 1);
                int src = n16 + (qp << 4);
                int sr = p & 1;
                int lo  = __shfl((int)pkP[0][nt][sr], src, 64);
                int hiv = __shfl((int)pkP[1][nt][sr], src, 64);
                bp[nt][p] = (unsigned int)((quad < 2) ? lo : hiv);
            }
        #pragma unroll
        for (int wt = 0; wt < 4; ++wt) {
            H8 af; af.u4 = sm128[(MEMT_OFF >> 4) + (wt*16 + n16)*64 + ((mtile*4 + quad) ^ swz)];
            #pragma unroll
            for (int nt = 0; nt < 2; ++nt) {
                H8 bf; bf.u[0]=bp[nt][0]; bf.u[1]=bp[nt][1]; bf.u[2]=bp[nt][2]; bf.u[3]=bp[nt][3];
                Oa[wt][nt] = __builtin_amdgcn_mfma_f32_16x16x32_f16(af.h8, bf.h8, Oa[wt][nt], 0, 0, 0);
            }
        }
    }

    // ---- store read_words ----
    #pragma unroll
    for (int nt = 0; nt < 2; ++nt) {
        float inv = 1.0f / ll[nt];
        int s = s0 + nt*16 + n16;
        #pragma unroll
        for (int wt = 0; wt < 4; ++wt) {
            float4 o = make_float4(Oa[wt][nt][0]*inv, Oa[wt][nt][1]*inv,
                                   Oa[wt][nt][2]*inv, Oa[wt][nt][3]*inv);
            *(float4*)&out[((size_t)(b*SSEQ + s)*4 + r)*WW + wt*16 + quad*4] = o;
        }
    }

    // ---- final_state (b == 255): recompute scores, store normalized wts ----
    if (b == BB - 1) {
        for (int mtile = 0; mtile < 16; ++mtile) {
            float4v Sa[2][2];
            #pragma unroll
            for (int msub = 0; msub < 2; ++msub)
                #pragma unroll
                for (int nt = 0; nt < 2; ++nt) Sa[msub][nt] = (float4v)0.f;
            #pragma unroll
            for (int msub = 0; msub < 2; ++msub) {
                int m = mtile*32 + msub*16 + n16;
                #pragma unroll
                for (int kc2 = 0; kc2 < 2; ++kc2) {
                    H8 af; af.u4 = sm128[m*8 + ((kc2*4 + quad) ^ swz)];
                    #pragma unroll
                    for (int nt = 0; nt < 2; ++nt) {
                        H8 bf; bf.u[0]=bq[kc2][nt][0]; bf.u[1]=bq[kc2][nt][1];
                               bf.u[2]=bq[kc2][nt][2]; bf.u[3]=bq[kc2][nt][3];
                        Sa[msub][nt] = __builtin_amdgcn_mfma_f32_16x16x32_f16(af.h8, bf.h8, Sa[msub][nt], 0, 0, 0);
                    }
                }
            }
            #pragma unroll
            for (int nt = 0; nt < 2; ++nt) {
                float inv = 1.0f / ll[nt];
                int s = s0 + nt*16 + n16;
                size_t base = (size_t)OUT1 + ((size_t)(s*4 + r) << 9);
                #pragma unroll
                for (int msub = 0; msub < 2; ++msub) {
                    float4 w4 = make_float4(
                        __builtin_amdgcn_exp2f(Sa[msub][nt][0] - Ml[nt]) * inv,
                        __builtin_amdgcn_exp2f(Sa[msub][nt][1] - Ml[nt]) * inv,
                        __builtin_amdgcn_exp2f(Sa[msub][nt][2] - Ml[nt]) * inv,
                        __builtin_amdgcn_exp2f(Sa[msub][nt][3] - Ml[nt]) * inv);
                    *(float4*)&out[base + mtile*32 + msub*16 + quad*4] = w4;
                }
            }
        }
    }
}

extern "C" void kernel_launch(void* const* d_in, const int* in_sizes, int n_in,
                              void* d_out, int out_size, void* d_ws, size_t ws_size,
                              hipStream_t stream) {
    const float* x    = (const float*)d_in[0];
    const int*   uid  = (const int*)  d_in[1];
    const float* uet  = (const float*)d_in[2];
    const float* Wp   = (const float*)d_in[3];
    const float* bp   = (const float*)d_in[4];
    const float* Wq   = (const float*)d_in[5];
    const float* mem  = (const float*)d_in[6];
    float* out = (float*)d_out;
    char* ws = (char*)d_ws;

    int useImg = (ws_size >= (size_t)WQT_OFF) ? 1 : 0;
    int useWqT = (ws_size >= (size_t)WQT_OFF + WQT_BYTES) ? 1 : 0;

    (void)hipFuncSetAttribute((const void*)prep_kernel,
                              hipFuncAttributeMaxDynamicSharedMemorySize, PREP_LDS);
    (void)hipFuncSetAttribute((const void*)attn_kernel,
                              hipFuncAttributeMaxDynamicSharedMemorySize, LDS_BYTES);

    if (useImg || useWqT)
        prep_kernel<<<400, 256, PREP_LDS, stream>>>(Wq, mem, ws, useImg, useWqT);

    attn_kernel<<<BB, 1024, LDS_BYTES, stream>>>(x, uid, uet, Wp, bp, Wq, mem, ws,
                                                 useImg, useWqT, out);
}

// Round 6
// 168.735 us; speedup vs baseline: 7.8223x; 1.0381x over previous
//
#include <hip/hip_runtime.h>
#include <math.h>

#define BB 256
#define SSEQ 128
#define INPUT 256
#define PD 128
#define EE 64
#define RW 256
#define MM 512
#define WW 64
#define KD 384          // IN_DIM

typedef _Float16 half8 __attribute__((ext_vector_type(8)));
typedef __fp16 fp16x2 __attribute__((ext_vector_type(2)));
typedef float float4v __attribute__((ext_vector_type(4)));

#define LOG2E 1.44269504088896f
#define OUT1 8388608u

// LDS byte layout.
// Phase A (prologue): [0,128K) = Wq x-part f16 image, chunk c = (k>>3)*256 + n, 8 halves (k%8) per 16B chunk.
// Phase B (flash):    [0,64K)  = mem f16 rows (chunk m*8 + (c^(m&7))),
//                     [64K,128K) = memT f16 (chunk w*64 + (cm^(w&7))).
// [128K, 128K+6K) f32 scratch.
#define MEMT_OFF 65536
#define F32_OFF  131072
#define LDS_BYTES (131072 + 6144)
#define UE_O 0
#define PE_O 64
#define QPE_O 192
#define QP_O 448                  // qpart [1024]

union H8 { half8 h8; unsigned int u[4]; uint4 u4; };

__device__ __forceinline__ unsigned int pk2(float a, float b) {
    union { fp16x2 h; unsigned int u; } p;
    p.h = __builtin_amdgcn_cvt_pkrtz(a, b);
    return p.u;
}

// ---------- single fused kernel: 256 blocks x 1024 threads (16 waves) ----------
__global__ void __launch_bounds__(1024, 4)
attn_kernel(const float* __restrict__ x, const int* __restrict__ user_id,
            const float* __restrict__ uet, const float* __restrict__ W_proc,
            const float* __restrict__ b_proc, const float* __restrict__ Wq,
            const float* __restrict__ memG, float* __restrict__ out)
{
    extern __shared__ char smraw[];
    unsigned short* smemu = (unsigned short*)smraw;
    unsigned int*   smw   = (unsigned int*)smraw;
    uint4*          sm128 = (uint4*)smraw;
    float*          smf   = (float*)(smraw + F32_OFF);

    const int t = threadIdx.x;
    const int b = blockIdx.x;
    const int lane = t & 63, wv = t >> 6;        // 16 waves
    const int n16 = lane & 15, quad = lane >> 4;
    const int r = wv & 3, sq = wv >> 2;          // sq 0..3
    const int s0 = sq * 32;
    const int swz = n16 & 7;

    const int uid = user_id[b];
    const int sid = uid & 15;
    const float* memB = memG + (size_t)sid * (MM*WW);
    const float* wqX  = Wq + (size_t)sid * KD * RW;

    if (t < EE) smf[UE_O + t] = uet[(size_t)uid*EE + t];

    // ---- Prologue A: Wq x-part (k<256, n<256) -> LDS f16 image [k/8][n][k%8] ----
    // coalesced 256B row reads; u32 LDS writes are 8-way banked (accepted).
    for (int i = 0; i < 32; ++i) {
        int idx = i*1024 + t;                    // 0..32767
        int n = idx & 255, kp = idx >> 8;        // kp = k/2, 0..127
        float w0 = wqX[(size_t)(2*kp)    *RW + n];
        float w1 = wqX[(size_t)(2*kp + 1)*RW + n];
        smw[((((kp>>2)*256 + n) << 2) | (kp & 3))] = pk2(w0, w1);
    }
    __syncthreads();                             // ue + Wq image ready

    // pe
    if (t < PD) {
        float a = b_proc[t];
        #pragma unroll
        for (int e = 0; e < EE; ++e) a = fmaf(smf[UE_O + e], W_proc[e*PD + t], a);
        smf[PE_O + t] = a;
    }
    __syncthreads();
    // qpe partials: qpe[n] = sum_k pe[k] * Wq[256+k][n], 4-way k-split
    {
        int n = t & 255, h = t >> 8;             // h 0..3
        float s = 0.f;
        const float* wr = wqX + (size_t)(256 + h*32)*RW + n;
        #pragma unroll 8
        for (int k = 0; k < 32; ++k) s = fmaf(smf[PE_O + h*32 + k], wr[(size_t)k*RW], s);
        smf[QP_O + h*256 + n] = s;
    }
    __syncthreads();
    if (t < 256) smf[QPE_O + t] = LOG2E * (smf[QP_O + t] + smf[QP_O + 256 + t]
                                         + smf[QP_O + 512 + t] + smf[QP_O + 768 + t]);
    __syncthreads();

    // ---- Phase Q: qT[n][s] over the x-part (k = 0..255); pe-part via qpe bias.
    //      A-fragments from the LDS Wq image (b128, conflict-free); B from x global.
    float4v qacc[4][2];
    #pragma unroll
    for (int mt = 0; mt < 4; ++mt)
        #pragma unroll
        for (int nt = 0; nt < 2; ++nt) qacc[mt][nt] = (float4v)0.f;

    const float* xB = x + (size_t)(b*SSEQ + s0) * INPUT;
    for (int kc = 0; kc < 8; ++kc) {
        H8 afr[4];
        #pragma unroll
        for (int mt = 0; mt < 4; ++mt)
            afr[mt].u4 = sm128[(kc*4 + quad)*256 + r*64 + mt*16 + n16];
        H8 bfr[2];
        #pragma unroll
        for (int nt = 0; nt < 2; ++nt) {
            const float* xg = xB + (size_t)(nt*16 + n16)*INPUT + kc*32 + quad*8;
            float4 a0 = *(const float4*)xg;
            float4 a1 = *(const float4*)(xg + 4);
            bfr[nt].u[0] = pk2(a0.x*LOG2E, a0.y*LOG2E);
            bfr[nt].u[1] = pk2(a0.z*LOG2E, a0.w*LOG2E);
            bfr[nt].u[2] = pk2(a1.x*LOG2E, a1.y*LOG2E);
            bfr[nt].u[3] = pk2(a1.z*LOG2E, a1.w*LOG2E);
        }
        #pragma unroll
        for (int mt = 0; mt < 4; ++mt)
            #pragma unroll
            for (int nt = 0; nt < 2; ++nt)
                qacc[mt][nt] = __builtin_amdgcn_mfma_f32_16x16x32_f16(afr[mt].h8, bfr[nt].h8, qacc[mt][nt], 0, 0, 0);
    }
    #pragma unroll
    for (int mt = 0; mt < 4; ++mt)
        #pragma unroll
        for (int reg = 0; reg < 4; ++reg) {
            float qv = smf[QPE_O + r*64 + mt*16 + quad*4 + reg];
            #pragma unroll
            for (int nt = 0; nt < 2; ++nt) qacc[mt][nt][reg] += qv;
        }
    unsigned int pkq[4][2][2];
    #pragma unroll
    for (int mt = 0; mt < 4; ++mt)
        #pragma unroll
        for (int nt = 0; nt < 2; ++nt) {
            pkq[mt][nt][0] = pk2(qacc[mt][nt][0], qacc[mt][nt][1]);
            pkq[mt][nt][1] = pk2(qacc[mt][nt][2], qacc[mt][nt][3]);
        }
    unsigned int bq[2][2][4];
    #pragma unroll
    for (int kc2 = 0; kc2 < 2; ++kc2)
        #pragma unroll
        for (int nt = 0; nt < 2; ++nt)
            #pragma unroll
            for (int p = 0; p < 4; ++p) {
                int qp = ((quad & 1) << 1) | (p >> 1);
                int src = n16 + (qp << 4);
                int sr = p & 1;
                int lo  = __shfl((int)pkq[kc2*2    ][nt][sr], src, 64);
                int hiv = __shfl((int)pkq[kc2*2 + 1][nt][sr], src, 64);
                bq[kc2][nt][p] = (unsigned int)((quad < 2) ? lo : hiv);
            }
    __syncthreads();                             // all waves done reading Wq image

    // ---- Prologue B: overwrite LDS with mem f16 images (convert + transpose) ----
    for (int i = 0; i < 4; ++i) {
        int id = t + i*1024;                     // 0..4095
        int m = id >> 3, cw = id & 7;
        const float* g = memB + m*64 + cw*8;
        float4 a0 = *(const float4*)g;
        float4 a1 = *(const float4*)(g + 4);
        sm128[m*8 + (cw ^ (m & 7))] =
            make_uint4(pk2(a0.x,a0.y), pk2(a0.z,a0.w), pk2(a1.x,a1.y), pk2(a1.z,a1.w));
    }
    __syncthreads();
    for (int i = 0; i < 4; ++i) {
        int id = t + i*1024;
        int w = id & 63, cm = id >> 6;
        unsigned int uu[4];
        #pragma unroll
        for (int p = 0; p < 4; ++p) {
            int m0 = cm*8 + 2*p, m1 = m0 + 1;
            unsigned short lo = smemu[m0*64 + (((w>>3) ^ (m0&7))<<3) + (w&7)];
            unsigned short hi = smemu[m1*64 + (((w>>3) ^ (m1&7))<<3) + (w&7)];
            uu[p] = (unsigned int)lo | ((unsigned int)hi << 16);
        }
        sm128[(MEMT_OFF >> 4) + w*64 + (cm ^ (w & 7))] = make_uint4(uu[0],uu[1],uu[2],uu[3]);
    }
    __syncthreads();

    // ================= per-wave flash loop, no more barriers =================
    float4v Oa[4][2];
    #pragma unroll
    for (int wt = 0; wt < 4; ++wt)
        #pragma unroll
        for (int nt = 0; nt < 2; ++nt) Oa[wt][nt] = (float4v)0.f;
    float Ml[2] = {-1e30f, -1e30f}, ll[2] = {0.f, 0.f};

    for (int mtile = 0; mtile < 16; ++mtile) {
        float4v Sa[2][2];
        #pragma unroll
        for (int msub = 0; msub < 2; ++msub)
            #pragma unroll
            for (int nt = 0; nt < 2; ++nt) Sa[msub][nt] = (float4v)0.f;
        #pragma unroll
        for (int msub = 0; msub < 2; ++msub) {
            int m = mtile*32 + msub*16 + n16;
            #pragma unroll
            for (int kc2 = 0; kc2 < 2; ++kc2) {
                H8 af; af.u4 = sm128[m*8 + ((kc2*4 + quad) ^ swz)];
                #pragma unroll
                for (int nt = 0; nt < 2; ++nt) {
                    H8 bf; bf.u[0]=bq[kc2][nt][0]; bf.u[1]=bq[kc2][nt][1];
                           bf.u[2]=bq[kc2][nt][2]; bf.u[3]=bq[kc2][nt][3];
                    Sa[msub][nt] = __builtin_amdgcn_mfma_f32_16x16x32_f16(af.h8, bf.h8, Sa[msub][nt], 0, 0, 0);
                }
            }
        }
        unsigned int pkP[2][2][2];
        #pragma unroll
        for (int nt = 0; nt < 2; ++nt) {
            float tm = Sa[0][nt][0];
            #pragma unroll
            for (int g = 1; g < 4; ++g) tm = fmaxf(tm, Sa[0][nt][g]);
            #pragma unroll
            for (int g = 0; g < 4; ++g) tm = fmaxf(tm, Sa[1][nt][g]);
            tm = fmaxf(tm, __shfl_xor(tm, 16, 64));
            tm = fmaxf(tm, __shfl_xor(tm, 32, 64));
            float Mn = fmaxf(Ml[nt], tm);
            float al = __builtin_amdgcn_exp2f(Ml[nt] - Mn);
            float pv[2][4]; float ts = 0.f;
            #pragma unroll
            for (int msub = 0; msub < 2; ++msub)
                #pragma unroll
                for (int g = 0; g < 4; ++g) {
                    pv[msub][g] = __builtin_amdgcn_exp2f(Sa[msub][nt][g] - Mn);
                    ts += pv[msub][g];
                }
            ts += __shfl_xor(ts, 16, 64);
            ts += __shfl_xor(ts, 32, 64);
            ll[nt] = al*ll[nt] + ts;
            Ml[nt] = Mn;
            pkP[0][nt][0] = pk2(pv[0][0], pv[0][1]); pkP[0][nt][1] = pk2(pv[0][2], pv[0][3]);
            pkP[1][nt][0] = pk2(pv[1][0], pv[1][1]); pkP[1][nt][1] = pk2(pv[1][2], pv[1][3]);
            #pragma unroll
            for (int wt = 0; wt < 4; ++wt)
                #pragma unroll
                for (int g = 0; g < 4; ++g) Oa[wt][nt][g] *= al;
        }
        unsigned int bp[2][4];
        #pragma unroll
        for (int nt = 0; nt < 2; ++nt)
            #pragma unroll
            for (int p = 0; p < 4; ++p) {
                int qp = ((quad & 1) << 1) | (p >> 1);
                int src = n16 + (qp << 4);
                int sr = p & 1;
                int lo  = __shfl((int)pkP[0][nt][sr], src, 64);
                int hiv = __shfl((int)pkP[1][nt][sr], src, 64);
                bp[nt][p] = (unsigned int)((quad < 2) ? lo : hiv);
            }
        #pragma unroll
        for (int wt = 0; wt < 4; ++wt) {
            H8 af; af.u4 = sm128[(MEMT_OFF >> 4) + (wt*16 + n16)*64 + ((mtile*4 + quad) ^ swz)];
            #pragma unroll
            for (int nt = 0; nt < 2; ++nt) {
                H8 bf; bf.u[0]=bp[nt][0]; bf.u[1]=bp[nt][1]; bf.u[2]=bp[nt][2]; bf.u[3]=bp[nt][3];
                Oa[wt][nt] = __builtin_amdgcn_mfma_f32_16x16x32_f16(af.h8, bf.h8, Oa[wt][nt], 0, 0, 0);
            }
        }
    }

    // ---- store read_words ----
    #pragma unroll
    for (int nt = 0; nt < 2; ++nt) {
        float inv = 1.0f / ll[nt];
        int s = s0 + nt*16 + n16;
        #pragma unroll
        for (int wt = 0; wt < 4; ++wt) {
            float4 o = make_float4(Oa[wt][nt][0]*inv, Oa[wt][nt][1]*inv,
                                   Oa[wt][nt][2]*inv, Oa[wt][nt][3]*inv);
            *(float4*)&out[((size_t)(b*SSEQ + s)*4 + r)*WW + wt*16 + quad*4] = o;
        }
    }

    // ---- final_state (b == 255): recompute scores, store normalized wts ----
    if (b == BB - 1) {
        for (int mtile = 0; mtile < 16; ++mtile) {
            float4v Sa[2][2];
            #pragma unroll
            for (int msub = 0; msub < 2; ++msub)
                #pragma unroll
                for (int nt = 0; nt < 2; ++nt) Sa[msub][nt] = (float4v)0.f;
            #pragma unroll
            for (int msub = 0; msub < 2; ++msub) {
                int m = mtile*32 + msub*16 + n16;
                #pragma unroll
                for (int kc2 = 0; kc2 < 2; ++kc2) {
                    H8 af; af.u4 = sm128[m*8 + ((kc2*4 + quad) ^ swz)];
                    #pragma unroll
                    for (int nt = 0; nt < 2; ++nt) {
                        H8 bf; bf.u[0]=bq[kc2][nt][0]; bf.u[1]=bq[kc2][nt][1];
                               bf.u[2]=bq[kc2][nt][2]; bf.u[3]=bq[kc2][nt][3];
                        Sa[msub][nt] = __builtin_amdgcn_mfma_f32_16x16x32_f16(af.h8, bf.h8, Sa[msub][nt], 0, 0, 0);
                    }
                }
            }
            #pragma unroll
            for (int nt = 0; nt < 2; ++nt) {
                float inv = 1.0f / ll[nt];
                int s = s0 + nt*16 + n16;
                size_t base = (size_t)OUT1 + ((size_t)(s*4 + r) << 9);
                #pragma unroll
                for (int msub = 0; msub < 2; ++msub) {
                    float4 w4 = make_float4(
                        __builtin_amdgcn_exp2f(Sa[msub][nt][0] - Ml[nt]) * inv,
                        __builtin_amdgcn_exp2f(Sa[msub][nt][1] - Ml[nt]) * inv,
                        __builtin_amdgcn_exp2f(Sa[msub][nt][2] - Ml[nt]) * inv,
                        __builtin_amdgcn_exp2f(Sa[msub][nt][3] - Ml[nt]) * inv);
                    *(float4*)&out[base + mtile*32 + msub*16 + quad*4] = w4;
                }
            }
        }
    }
}

extern "C" void kernel_launch(void* const* d_in, const int* in_sizes, int n_in,
                              void* d_out, int out_size, void* d_ws, size_t ws_size,
                              hipStream_t stream) {
    const float* x    = (const float*)d_in[0];
    const int*   uid  = (const int*)  d_in[1];
    const float* uet  = (const float*)d_in[2];
    const float* Wp   = (const float*)d_in[3];
    const float* bp   = (const float*)d_in[4];
    const float* Wq   = (const float*)d_in[5];
    const float* mem  = (const float*)d_in[6];
    float* out = (float*)d_out;

    (void)hipFuncSetAttribute((const void*)attn_kernel,
                              hipFuncAttributeMaxDynamicSharedMemorySize, LDS_BYTES);
    attn_kernel<<<BB, 1024, LDS_BYTES, stream>>>(x, uid, uet, Wp, bp, Wq, mem, out);
}